// Round 9
// baseline (9060.011 us; speedup 1.0000x reference)
//
#include <hip/hip_runtime.h>
#include <math.h>

#define NSTEPS 200
#define NT     512          // 8 waves; each wave owns 16 output cols
#define BR     64
#define SQDT_F 0.07071067811865475f
#define DT_F   0.005f
#define LOSCL  4096.0f            // 2^12
#define LOINV  2.44140625e-4f     // 2^-12

typedef float  f32x4 __attribute__((ext_vector_type(4)));
typedef short  s16x8 __attribute__((ext_vector_type(8)));
typedef _Float16 h16x8 __attribute__((ext_vector_type(8)));
typedef unsigned short u16;
typedef unsigned short us4 __attribute__((ext_vector_type(4)));

// prepacked weight offsets in u16 units (each 128x128 matrix = 32768 u16 as hi/lo frags)
#define ENC_OFF 0
#define W1_OFF  32768
#define W2_OFF  65536
#define WG0_OFF 98304
#define WG1_OFF 131072
#define DEC_OFF 163840
#define WPK_TOT 196608

// ---- fp16 scaled two-term split: x ~= hi + lo*2^-12, |err| <= ~2^-23 |x| ----
__device__ __forceinline__ u16 f2h(float v) {
    _Float16 h = (_Float16)v;                       // v_cvt_f16_f32, RNE
    return __builtin_bit_cast(u16, h);
}
__device__ __forceinline__ float h2f(u16 u) {
    return (float)__builtin_bit_cast(_Float16, u);
}
__device__ __forceinline__ u16 split_hi(float v) { return f2h(v); }
__device__ __forceinline__ u16 split_lo(float v, u16 hi) {
    return f2h((v - h2f(hi)) * LOSCL);              // v-hi exact in fp32; *2^12 exact
}
__device__ __forceinline__ float gelu_exact(float x) {
    // exact erf GELU: approx GELU re-rolls the chaotic trajectory (rounds 2/3).
    return 0.5f * x * (1.0f + erff(x * 0.70710678118654752f));
}

// MFMA via builtin: compiler models hazards (r6/r7 inline-asm MFMA NaN'd).
__device__ __forceinline__ void mfma16(f32x4& d, s16x8 a, s16x8 b) {
    d = __builtin_amdgcn_mfma_f32_16x16x32_f16(
            __builtin_bit_cast(h16x8, a), __builtin_bit_cast(h16x8, b), d, 0, 0, 0);
}
__device__ __forceinline__ s16x8 ldf(const u16* p) {
    return *reinterpret_cast<const s16x8*>(p);
}

// ---------------- weight prepack: fp32 -> fp16 hi / scaled-lo fragments ----------------
// frag layout: base + ((nt*4 + kc)*2 + term)*512 + lane*8 + i   (u16 units)
// element: B[k = kc*32 + (lane>>4)*8 + i][n = nt*16 + (lane&15)]
// sigma column-deinterleaved: WG0 = sig_w[:,0::2], WG1 = sig_w[:,1::2]
__global__ void prepack(const float* __restrict__ enc_w, const float* __restrict__ mu_w1,
                        const float* __restrict__ mu_w2, const float* __restrict__ sig_w,
                        const float* __restrict__ dec_w, u16* __restrict__ wpk)
{
    int u = blockIdx.x * 256 + threadIdx.x;
    if (u >= WPK_TOT) return;
    int mat  = u >> 15;
    int r    = u & 32767;
    int i    = r & 7;
    int lane = (r >> 3) & 63;
    int term = (r >> 9) & 1;
    int kc   = (r >> 10) & 3;
    int nt   = (r >> 12) & 7;
    int k = kc * 32 + (lane >> 4) * 8 + i;
    int n = nt * 16 + (lane & 15);
    float v;
    switch (mat) {
        case 0:  v = enc_w[k * 128 + n];         break;
        case 1:  v = mu_w1[k * 128 + n];         break;
        case 2:  v = mu_w2[k * 128 + n];         break;
        case 3:  v = sig_w[k * 256 + 2 * n];     break;
        case 4:  v = sig_w[k * 256 + 2 * n + 1]; break;
        default: v = dec_w[k * 128 + n];         break;
    }
    u16 hi = split_hi(v);
    wpk[u] = term ? split_lo(v, hi) : hi;
}

// ---------------- main fused SDE kernel ----------------
// Register/occupancy plan (r8 post-mortem: allocator targeted 128 VGPRs at
// 2 blocks/CU and spilled the 128-reg resident weights to scratch -> 12.8 GB
// HBM): LDS = 132 KB forces 1 block/CU; waves_per_eu(2,2) -> 256-reg budget;
// resident set cut to 96 VGPRs (sigma lo-term weights live in LDS, sigma
// pass split g0/g1 to cap live accumulators at 32).
__global__ __launch_bounds__(NT)
__attribute__((amdgpu_waves_per_eu(2, 2)))
void sde_mfma(
    const float* __restrict__ y, const float* __restrict__ noise,
    const float* __restrict__ enc_b, const float* __restrict__ mu_b1,
    const float* __restrict__ mu_b2, const float* __restrict__ sig_b,
    const float* __restrict__ dec_b, const u16* __restrict__ wpk,
    float* __restrict__ out, int Btot)
{
    __shared__ __align__(16) u16 zbh[8192];
    __shared__ __align__(16) u16 zbl[8192];
    __shared__ __align__(16) u16 hbh[8192];
    __shared__ __align__(16) u16 hbl[8192];
    __shared__ __align__(16) u16 lg0[16384];   // Wg0 lo-term frags (all 8 strips)
    __shared__ __align__(16) u16 lg1[16384];   // Wg1 lo-term frags
    __shared__ float nsb[2][128];

    const int tid  = threadIdx.x;
    const int lane = tid & 63, wid = tid >> 6;      // wid 0..7
    const int ln   = lane & 15, lg = lane >> 4;
    const size_t brow = (size_t)blockIdx.x * BR;

    const int n0 = wid * 16 + ln;                   // this thread's single col
    const float be0 = enc_b[n0];
    const float b10 = mu_b1[n0];
    const float b20 = mu_b2[n0];
    const float bg0 = sig_b[2 * n0];
    const float bg1 = sig_b[2 * n0 + 1];
    const float bd0 = dec_b[n0];

    // ---- resident weight strips: 24 s16x8 = 96 VGPRs ----
    s16x8 w1h[4], w1l[4], w2h[4], w2l[4];
    s16x8 g0h[4], g1h[4];
    #pragma unroll
    for (int kc = 0; kc < 4; kc++) {
        int fo = (((wid << 2) | kc) << 10) + (lane << 3);
        w1h[kc] = ldf(wpk + W1_OFF  + fo); w1l[kc] = ldf(wpk + W1_OFF  + fo + 512);
        w2h[kc] = ldf(wpk + W2_OFF  + fo); w2l[kc] = ldf(wpk + W2_OFF  + fo + 512);
        g0h[kc] = ldf(wpk + WG0_OFF + fo);
        g1h[kc] = ldf(wpk + WG1_OFF + fo);
    }

    // ---- stage sigma lo-term weights into LDS (one-shot) ----
    // lg[strip*512 + off] = wpk[OFF + strip*1024 + 512 + off], strip = nt*4+kc
    #pragma unroll
    for (int c = 0; c < 4; c++) {
        int i = c * NT + tid;                       // 0..2047, 8 u16 each
        int so = ((i >> 6) << 10) + 512 + ((i & 63) << 3);
        *reinterpret_cast<s16x8*>(lg0 + (i << 3)) = ldf(wpk + WG0_OFF + so);
        *reinterpret_cast<s16x8*>(lg1 + (i << 3)) = ldf(wpk + WG1_OFF + so);
    }

    float zr[4][4];   // z state: elem (m = 16*mt + 4*lg + r, n = n0)

    // ---- stage y into zb (fp16 hi/lo, swizzled) ----
    #pragma unroll
    for (int c = 0; c < 4; c++) {
        int q = c * NT + tid;                 // 0..2047
        int row = q >> 5, k4 = (q & 31) << 2;
        const float4 v = *reinterpret_cast<const float4*>(y + (brow + row) * 128 + k4);
        int idx = row * 128 + ((((k4 >> 3) ^ (row & 7))) << 3) + (k4 & 7);
        float vv[4] = {v.x, v.y, v.z, v.w};
        us4 hv, lv;
        #pragma unroll
        for (int e = 0; e < 4; e++) {
            u16 h = split_hi(vv[e]);
            u16 l = split_lo(vv[e], h);
            hv[e] = h; lv[e] = l;
        }
        *reinterpret_cast<us4*>(zbh + idx) = hv;
        *reinterpret_cast<us4*>(zbl + idx) = lv;
    }
    __syncthreads();

    // ---- encoder: z0 = gelu_exact(y @ enc_w + enc_b) ----
    {
        f32x4 a0[4], a1[4];
        #pragma unroll
        for (int mt = 0; mt < 4; mt++) {
            a0[mt] = f32x4{be0, be0, be0, be0};
            a1[mt] = f32x4{0, 0, 0, 0};
        }
        #pragma unroll
        for (int kc = 0; kc < 4; kc++) {
            s16x8 ah[4], al[4];
            #pragma unroll
            for (int mt = 0; mt < 4; mt++) {
                int row = mt * 16 + ln;
                int idx = row * 128 + ((((kc << 2) | lg) ^ (row & 7)) << 3);
                ah[mt] = ldf(zbh + idx);
                al[mt] = ldf(zbl + idx);
            }
            int fo = (((wid << 2) | kc) << 10) + (lane << 3);
            s16x8 bh = ldf(wpk + ENC_OFF + fo);
            s16x8 bl = ldf(wpk + ENC_OFF + fo + 512);
            #pragma unroll
            for (int mt = 0; mt < 4; mt++) {
                mfma16(a0[mt], ah[mt], bh);
                mfma16(a1[mt], al[mt], bh);
                mfma16(a1[mt], ah[mt], bl);
            }
        }
        #pragma unroll
        for (int mt = 0; mt < 4; mt++)
            #pragma unroll
            for (int r = 0; r < 4; r++)
                zr[mt][r] = gelu_exact(fmaf(a1[mt][r], LOINV, a0[mt][r]));
    }
    __syncthreads();   // all reads of y-tile done

    // write z0 into zb; stage noise for t=0
    #pragma unroll
    for (int mt = 0; mt < 4; mt++)
        #pragma unroll
        for (int r = 0; r < 4; r++) {
            int m = 16 * mt + 4 * lg + r;
            int idx = m * 128 + ((((n0 >> 3) ^ (m & 7))) << 3) + (n0 & 7);
            u16 h = split_hi(zr[mt][r]);
            zbh[idx] = h;
            zbl[idx] = split_lo(zr[mt][r], h);
        }
    if (tid < 128) nsb[0][tid] = noise[brow * 2 + tid];
    __syncthreads();

    // ---- 200 Euler-Maruyama steps, 2 barriers each, zero global loads except noise ----
    for (int t = 0; t < NSTEPS; t++) {
        {   // prefetch next step's noise into the other buffer
            int tn = (t + 1 < NSTEPS) ? (t + 1) : t;
            if (tid < 128) nsb[(t + 1) & 1][tid] = noise[((size_t)tn * Btot + brow) * 2 + tid];
        }
        // pass 1 — G1: h = gelu(z @ W1 + b1) -> hb (W1 resident)
        {
            f32x4 a0[4], a1[4];
            #pragma unroll
            for (int mt = 0; mt < 4; mt++) {
                a0[mt] = f32x4{b10, b10, b10, b10};
                a1[mt] = f32x4{0, 0, 0, 0};
            }
            #pragma unroll
            for (int kc = 0; kc < 4; kc++) {
                s16x8 ah[4], al[4];
                #pragma unroll
                for (int mt = 0; mt < 4; mt++) {
                    int row = mt * 16 + ln;
                    int idx = row * 128 + ((((kc << 2) | lg) ^ (row & 7)) << 3);
                    ah[mt] = ldf(zbh + idx);
                    al[mt] = ldf(zbl + idx);
                }
                #pragma unroll
                for (int mt = 0; mt < 4; mt++) {
                    mfma16(a0[mt], ah[mt], w1h[kc]);
                    mfma16(a1[mt], al[mt], w1h[kc]);
                    mfma16(a1[mt], ah[mt], w1l[kc]);
                }
            }
            #pragma unroll
            for (int mt = 0; mt < 4; mt++)
                #pragma unroll
                for (int r = 0; r < 4; r++) {
                    float hv = gelu_exact(fmaf(a1[mt][r], LOINV, a0[mt][r]));
                    int m = 16 * mt + 4 * lg + r;
                    int idx = m * 128 + ((((n0 >> 3) ^ (m & 7))) << 3) + (n0 & 7);
                    u16 h = split_hi(hv);
                    hbh[idx] = h;
                    hbl[idx] = split_lo(hv, h);
                }
        }
        // pass 2a — g0 = z @ Wg0 + bg0; z += g0*dw0 (g0h resident, g0-lo from LDS)
        const float* np = nsb[t & 1];
        {
            f32x4 p0[4], p1[4];
            #pragma unroll
            for (int mt = 0; mt < 4; mt++) {
                p0[mt] = f32x4{bg0, bg0, bg0, bg0};
                p1[mt] = f32x4{0, 0, 0, 0};
            }
            #pragma unroll
            for (int kc = 0; kc < 4; kc++) {
                s16x8 ah[4], al[4];
                #pragma unroll
                for (int mt = 0; mt < 4; mt++) {
                    int row = mt * 16 + ln;
                    int idx = row * 128 + ((((kc << 2) | lg) ^ (row & 7)) << 3);
                    ah[mt] = ldf(zbh + idx);
                    al[mt] = ldf(zbl + idx);
                }
                s16x8 bl = ldf(lg0 + (((wid << 2) | kc) << 9) + (lane << 3));
                #pragma unroll
                for (int mt = 0; mt < 4; mt++) {
                    mfma16(p0[mt], ah[mt], g0h[kc]);
                    mfma16(p1[mt], al[mt], g0h[kc]);
                    mfma16(p1[mt], ah[mt], bl);
                }
            }
            #pragma unroll
            for (int mt = 0; mt < 4; mt++)
                #pragma unroll
                for (int r = 0; r < 4; r++) {
                    int m = 16 * mt + 4 * lg + r;
                    float dw0 = np[2 * m] * SQDT_F;
                    zr[mt][r] = fmaf(fmaf(p1[mt][r], LOINV, p0[mt][r]), dw0, zr[mt][r]);
                }
        }
        // pass 2b — g1 = z @ Wg1 + bg1; z += g1*dw1 (g1h resident, g1-lo from LDS)
        {
            f32x4 p0[4], p1[4];
            #pragma unroll
            for (int mt = 0; mt < 4; mt++) {
                p0[mt] = f32x4{bg1, bg1, bg1, bg1};
                p1[mt] = f32x4{0, 0, 0, 0};
            }
            #pragma unroll
            for (int kc = 0; kc < 4; kc++) {
                s16x8 ah[4], al[4];
                #pragma unroll
                for (int mt = 0; mt < 4; mt++) {
                    int row = mt * 16 + ln;
                    int idx = row * 128 + ((((kc << 2) | lg) ^ (row & 7)) << 3);
                    ah[mt] = ldf(zbh + idx);
                    al[mt] = ldf(zbl + idx);
                }
                s16x8 bl = ldf(lg1 + (((wid << 2) | kc) << 9) + (lane << 3));
                #pragma unroll
                for (int mt = 0; mt < 4; mt++) {
                    mfma16(p0[mt], ah[mt], g1h[kc]);
                    mfma16(p1[mt], al[mt], g1h[kc]);
                    mfma16(p1[mt], ah[mt], bl);
                }
            }
            #pragma unroll
            for (int mt = 0; mt < 4; mt++)
                #pragma unroll
                for (int r = 0; r < 4; r++) {
                    int m = 16 * mt + 4 * lg + r;
                    float dw1 = np[2 * m + 1] * SQDT_F;
                    zr[mt][r] = fmaf(fmaf(p1[mt][r], LOINV, p0[mt][r]), dw1, zr[mt][r]);
                }
        }
        __syncthreads();   // bar1: hb visible; all zb reads complete

        // pass 3 — G2: drift = h @ W2 + b2; z += drift*dt; rewrite zb (W2 resident)
        {
            f32x4 a0[4], a1[4];
            #pragma unroll
            for (int mt = 0; mt < 4; mt++) {
                a0[mt] = f32x4{b20, b20, b20, b20};
                a1[mt] = f32x4{0, 0, 0, 0};
            }
            #pragma unroll
            for (int kc = 0; kc < 4; kc++) {
                s16x8 ah[4], al[4];
                #pragma unroll
                for (int mt = 0; mt < 4; mt++) {
                    int row = mt * 16 + ln;
                    int idx = row * 128 + ((((kc << 2) | lg) ^ (row & 7)) << 3);
                    ah[mt] = ldf(hbh + idx);
                    al[mt] = ldf(hbl + idx);
                }
                #pragma unroll
                for (int mt = 0; mt < 4; mt++) {
                    mfma16(a0[mt], ah[mt], w2h[kc]);
                    mfma16(a1[mt], al[mt], w2h[kc]);
                    mfma16(a1[mt], ah[mt], w2l[kc]);
                }
            }
            #pragma unroll
            for (int mt = 0; mt < 4; mt++)
                #pragma unroll
                for (int r = 0; r < 4; r++) {
                    float v = fmaf(fmaf(a1[mt][r], LOINV, a0[mt][r]), DT_F, zr[mt][r]);
                    zr[mt][r] = v;
                    int m = 16 * mt + 4 * lg + r;
                    int idx = m * 128 + ((((n0 >> 3) ^ (m & 7))) << 3) + (n0 & 7);
                    u16 h = split_hi(v);
                    zbh[idx] = h;
                    zbl[idx] = split_lo(v, h);
                }
        }
        __syncthreads();   // bar2: new zb visible
    }

    // ---- decoder: out = z @ dec_w + dec_b ----
    {
        f32x4 a0[4], a1[4];
        #pragma unroll
        for (int mt = 0; mt < 4; mt++) {
            a0[mt] = f32x4{bd0, bd0, bd0, bd0};
            a1[mt] = f32x4{0, 0, 0, 0};
        }
        #pragma unroll
        for (int kc = 0; kc < 4; kc++) {
            s16x8 ah[4], al[4];
            #pragma unroll
            for (int mt = 0; mt < 4; mt++) {
                int row = mt * 16 + ln;
                int idx = row * 128 + ((((kc << 2) | lg) ^ (row & 7)) << 3);
                ah[mt] = ldf(zbh + idx);
                al[mt] = ldf(zbl + idx);
            }
            int fo = (((wid << 2) | kc) << 10) + (lane << 3);
            s16x8 bh = ldf(wpk + DEC_OFF + fo);
            s16x8 bl = ldf(wpk + DEC_OFF + fo + 512);
            #pragma unroll
            for (int mt = 0; mt < 4; mt++) {
                mfma16(a0[mt], ah[mt], bh);
                mfma16(a1[mt], al[mt], bh);
                mfma16(a1[mt], ah[mt], bl);
            }
        }
        #pragma unroll
        for (int mt = 0; mt < 4; mt++)
            #pragma unroll
            for (int r = 0; r < 4; r++) {
                int m = 16 * mt + 4 * lg + r;
                out[(brow + m) * 128 + n0] = fmaf(a1[mt][r], LOINV, a0[mt][r]);
            }
    }
}

extern "C" void kernel_launch(void* const* d_in, const int* in_sizes, int n_in,
                              void* d_out, int out_size, void* d_ws, size_t ws_size,
                              hipStream_t stream) {
    const float* y     = (const float*)d_in[0];
    const float* noise = (const float*)d_in[1];
    const float* enc_w = (const float*)d_in[2];
    const float* enc_b = (const float*)d_in[3];
    const float* mu_w1 = (const float*)d_in[4];
    const float* mu_b1 = (const float*)d_in[5];
    const float* mu_w2 = (const float*)d_in[6];
    const float* mu_b2 = (const float*)d_in[7];
    const float* sig_w = (const float*)d_in[8];
    const float* sig_b = (const float*)d_in[9];
    const float* dec_w = (const float*)d_in[10];
    const float* dec_b = (const float*)d_in[11];
    float* out = (float*)d_out;
    u16* wpk = (u16*)d_ws;

    const int Btot = in_sizes[0] / 128;     // 32768
    prepack<<<(WPK_TOT + 255) / 256, 256, 0, stream>>>(enc_w, mu_w1, mu_w2, sig_w, dec_w, wpk);
    sde_mfma<<<Btot / BR, NT, 0, stream>>>(y, noise, enc_b, mu_b1, mu_b2, sig_b, dec_b,
                                           wpk, out, Btot);
}